// Round 7
// baseline (642.077 us; speedup 1.0000x reference)
//
#include <hip/hip_runtime.h>

#define T_TOK 2048
#define HD    2048
#define NE    32
#define ID    768
#define TOPK  8
#define NPAIR (T_TOK * TOPK)
#define MAXT  160                            // max padded tiles: NPAIR/128 + NE

typedef short bf16x8 __attribute__((ext_vector_type(8)));
typedef float f32x4  __attribute__((ext_vector_type(4)));

__device__ inline unsigned short f2bf(float f) {
    unsigned u = __builtin_bit_cast(unsigned, f);
    u += 0x7FFF + ((u >> 16) & 1);          // round-to-nearest-even
    return (unsigned short)(u >> 16);
}

__device__ inline void gload16(const void* g, void* l) {
    __builtin_amdgcn_global_load_lds(
        (const __attribute__((address_space(1))) unsigned*)g,
        (__attribute__((address_space(3))) unsigned*)l, 16, 0, 0);
}

// ================= fused prep: transposes (async 64x256 strips) + cvt_x + router =================
// Strip: src [R][C] f32 rows r0..r0+63, cols c0..c0+255 -> dst [C][R] bf16.
// Phase 1: 16x global_load_lds per thread (no VGPR cost -> regalloc can't serialize it).
// LDS = 64 rows x 1KB, linear dest; 16B-chunk XOR swizzle (key = row>>3) applied on the
// GLOBAL source address (rule #21). Phase 2: 8x ds_read_b32 (2 lanes/bank = free),
// f2bf+pack, 16B stores in 128B runs.

#define NT_GU2 3072                          // (HD/64)*(ID/256)*NE = 32*3*32
#define NT_D2  3072                          // (ID/64)*(HD/256)*NE = 12*8*32
#define NB_CVT 2048                          // T_TOK*HD/(256*8)
#define NB_RTR 2048                          // T_TOK

__device__ inline void transpose_strip(const float* __restrict__ src, unsigned short* __restrict__ dst,
                                       int R, int C, int r0, int c0, char* lds) {
    int tid = threadIdx.x;
    int w = tid >> 6, l = tid & 63;
    // phase 1: async loads. slot s = LDS row; lane l writes physical chunk l,
    // sourcing global logical chunk l ^ ((s>>3)&7).
    #pragma unroll
    for (int q = 0; q < 16; ++q) {
        int s = w * 16 + q;
        const float* gp = src + (size_t)(r0 + s) * C + c0 + ((l ^ ((s >> 3) & 7)) << 2);
        gload16(gp, lds + s * 1024);         // wave-uniform LDS base; HW adds lane*16
    }
    __syncthreads();
    // phase 2: output chunk idx -> dst row c (= src col), r-octet tt; read 8 f32 down rows
    #pragma unroll
    for (int jj = 0; jj < 8; ++jj) {
        int idx = tid + 256 * jj;            // 0..2047
        int c = idx >> 3, tt = idx & 7;
        const char* base = lds + tt * 8192 + ((((c >> 2) ^ tt) << 4) | ((c & 3) << 2));
        unsigned short o[8];
        #pragma unroll
        for (int j = 0; j < 8; ++j)
            o[j] = f2bf(*(const float*)(base + j * 1024));
        uint4 v;
        unsigned* pv = (unsigned*)&v;
        pv[0] = (unsigned)o[0] | ((unsigned)o[1] << 16);
        pv[1] = (unsigned)o[2] | ((unsigned)o[3] << 16);
        pv[2] = (unsigned)o[4] | ((unsigned)o[5] << 16);
        pv[3] = (unsigned)o[6] | ((unsigned)o[7] << 16);
        *(uint4*)&dst[(size_t)(c0 + c) * R + r0 + 8 * tt] = v;
    }
}

__global__ __launch_bounds__(256)
void prep_all(const float* __restrict__ x, const float* __restrict__ wg,
              const float* __restrict__ wgp, const float* __restrict__ wup,
              const float* __restrict__ wdp,
              unsigned short* __restrict__ X16,
              unsigned short* __restrict__ WG, unsigned short* __restrict__ WU,
              unsigned short* __restrict__ WD,
              int* __restrict__ topk_idx, float* __restrict__ topk_w,
              int* __restrict__ counts) {
    __shared__ __align__(16) char lds[65536];
    int bid = blockIdx.x;

    if (bid < NT_GU2) {                      // WG: [HD][ID] -> [ID][HD]
        int e = bid / 96, ti = bid % 96;
        int r0 = (ti & 31) * 64, c0 = (ti >> 5) * 256;  // r over HD(32), c over ID(3)
        transpose_strip(wgp + (size_t)e * HD * ID, WG + (size_t)e * HD * ID, HD, ID, r0, c0, lds);
        return;
    }
    bid -= NT_GU2;
    if (bid < NT_GU2) {                      // WU
        int e = bid / 96, ti = bid % 96;
        int r0 = (ti & 31) * 64, c0 = (ti >> 5) * 256;
        transpose_strip(wup + (size_t)e * HD * ID, WU + (size_t)e * HD * ID, HD, ID, r0, c0, lds);
        return;
    }
    bid -= NT_GU2;
    if (bid < NT_D2) {                       // WD: [ID][HD] -> [HD][ID]
        int e = bid / 96, ti = bid % 96;
        int r0 = (ti % 12) * 64, c0 = (ti / 12) * 256;  // r over ID(12), c over HD(8)
        transpose_strip(wdp + (size_t)e * ID * HD, WD + (size_t)e * ID * HD, ID, HD, r0, c0, lds);
        return;
    }
    bid -= NT_D2;
    if (bid < NB_CVT) {                      // X -> bf16
        int i = bid * 256 + threadIdx.x;
        const float4* src = (const float4*)x + (size_t)i * 2;
        float4 a = src[0], b = src[1];
        uint4 r;
        r.x = (unsigned)f2bf(a.x) | ((unsigned)f2bf(a.y) << 16);
        r.y = (unsigned)f2bf(a.z) | ((unsigned)f2bf(a.w) << 16);
        r.z = (unsigned)f2bf(b.x) | ((unsigned)f2bf(b.y) << 16);
        r.w = (unsigned)f2bf(b.z) | ((unsigned)f2bf(b.w) << 16);
        *(uint4*)(X16 + (size_t)i * 8) = r;
        return;
    }
    bid -= NB_CVT;
    {                                        // router, one block per token
        int t = bid;
        int tid = threadIdx.x;
        int e = tid & 31, seg = tid >> 5;
        const float* xr = x + (size_t)t * HD + seg * 256;
        const float* wp = wg + (size_t)(seg * 256) * NE + e;
        float acc = 0.f;
        #pragma unroll 4
        for (int j = 0; j < 256; ++j) acc += xr[j] * wp[j * NE];
        float* part = (float*)lds;           // [8][33]
        float* lg = part + 8 * 33;           // [32]
        part[seg * 33 + e] = acc;
        __syncthreads();
        if (tid < 32) {
            float s = 0.f;
            #pragma unroll
            for (int g = 0; g < 8; ++g) s += part[g * 33 + tid];
            lg[tid] = s;
        }
        __syncthreads();
        if (tid == 0) {
            float m = lg[0];
            for (int i = 1; i < 32; ++i) m = fmaxf(m, lg[i]);
            for (int i = 0; i < 32; ++i) lg[i] = __expf(lg[i] - m);
            int   idxs[TOPK]; float wv[TOPK]; float wsum = 0.f;
            #pragma unroll
            for (int k = 0; k < TOPK; ++k) {
                float best = -1.f; int bi = 0;
                for (int i = 0; i < 32; ++i) if (lg[i] > best) { best = lg[i]; bi = i; }
                idxs[k] = bi; wv[k] = best; wsum += best; lg[bi] = -1.f;
            }
            #pragma unroll
            for (int k = 0; k < TOPK; ++k) {
                topk_idx[t * TOPK + k] = idxs[k];
                topk_w[t * TOPK + k]   = wv[k] / wsum;
                atomicAdd(&counts[idxs[k]], 1);
            }
        }
    }
}

// ---------------- build padded tile table (1 thread; negligible) ----------------
__global__ void build_tiles(const int* __restrict__ counts, int* __restrict__ cursor,
                            int* __restrict__ tE, int* __restrict__ tStart,
                            int* __restrict__ tCnt) {
    if (threadIdx.x == 0 && blockIdx.x == 0) {
        int run = 0, nt = 0;
        for (int e = 0; e < NE; ++e) {
            cursor[e] = run;
            int c = counts[e];
            int nte = (c + 127) >> 7;
            for (int j = 0; j < nte; ++j) {
                tE[nt] = e;
                tStart[nt] = run + j * 128;
                tCnt[nt] = (c - j * 128 < 128) ? (c - j * 128) : 128;
                ++nt;
            }
            run += nte * 128;
        }
        for (; nt < MAXT; ++nt) { tE[nt] = -1; tStart[nt] = 0; tCnt[nt] = 0; }
    }
}

__global__ void scatter_kernel(const int* __restrict__ topk_idx, int* __restrict__ cursor,
                               int* __restrict__ token_list) {
    int i = blockIdx.x * 256 + threadIdx.x;
    int e = topk_idx[i];
    int pos = atomicAdd(&cursor[e], 1);
    token_list[pos] = i;
}

// ---------------- GEMM1: act = silu(X Wg) * (X Wu); tile 128pair x 128i ----------------
__global__ __launch_bounds__(256, 2)
void gemm1_kernel(const unsigned short* __restrict__ X16,
                  const unsigned short* __restrict__ WG, const unsigned short* __restrict__ WU,
                  const int* __restrict__ token_list,
                  const int* __restrict__ tE, const int* __restrict__ tStart,
                  const int* __restrict__ tCnt, unsigned short* __restrict__ act16) {
    int tile = blockIdx.x / 6, it = blockIdx.x % 6;
    int e = tE[tile];
    if (e < 0) return;
    int start = tStart[tile], cnt = tCnt[tile];
    int i0 = it * 128;

    __shared__ __align__(16) unsigned short As[128 * 64];
    __shared__ __align__(16) unsigned short Bg[128 * 64];
    __shared__ __align__(16) unsigned short Bu[128 * 64];
    __shared__ int rowTok[128];

    int tid = threadIdx.x;
    if (tid < 128)
        rowTok[tid] = (tid < cnt) ? (token_list[start + tid] >> 3) : 0;
    __syncthreads();

    int lane = tid & 63, w = tid >> 6;
    int sub = lane & 7, lrow = lane >> 3;

    const unsigned short* aP[4]; const unsigned short* gP[4]; const unsigned short* uP[4];
    #pragma unroll
    for (int c = 0; c < 4; ++c) {
        int q = w * 4 + c;
        int r = q * 8 + lrow;
        int chunk = (sub ^ (r & 7)) * 8;
        aP[c] = X16 + (size_t)rowTok[r] * HD + chunk;
        gP[c] = WG + ((size_t)e * ID + i0 + r) * HD + chunk;
        uP[c] = WU + ((size_t)e * ID + i0 + r) * HD + chunk;
    }

    f32x4 accg[4][4], accu[4][4];
    #pragma unroll
    for (int m = 0; m < 4; ++m)
        #pragma unroll
        for (int n = 0; n < 4; ++n) {
            f32x4 z = {0.f, 0.f, 0.f, 0.f};
            accg[m][n] = z; accu[m][n] = z;
        }

    int wm = w >> 1, wn = w & 1, l15 = lane & 15, lhi = lane >> 4;
    const bf16x8* Af = (const bf16x8*)As;
    const bf16x8* Gf = (const bf16x8*)Bg;
    const bf16x8* Uf = (const bf16x8*)Bu;

    for (int k0 = 0; k0 < HD; k0 += 64) {
        #pragma unroll
        for (int c = 0; c < 4; ++c) {
            int q = w * 4 + c;
            gload16(aP[c] + k0, (char*)As + q * 1024);
            gload16(gP[c] + k0, (char*)Bg + q * 1024);
            gload16(uP[c] + k0, (char*)Bu + q * 1024);
        }
        __syncthreads();
        #pragma unroll
        for (int ks = 0; ks < 2; ++ks) {
            int cc = ks * 4 + lhi;
            bf16x8 a[4], bg[4], bu[4];
            #pragma unroll
            for (int m = 0; m < 4; ++m) { int r = wm * 64 + m * 16 + l15; a[m] = Af[r * 8 + (cc ^ (r & 7))]; }
            #pragma unroll
            for (int n = 0; n < 4; ++n) {
                int r = wn * 64 + n * 16 + l15;
                bg[n] = Gf[r * 8 + (cc ^ (r & 7))];
                bu[n] = Uf[r * 8 + (cc ^ (r & 7))];
            }
            #pragma unroll
            for (int m = 0; m < 4; ++m)
                #pragma unroll
                for (int n = 0; n < 4; ++n) {
                    accg[m][n] = __builtin_amdgcn_mfma_f32_16x16x32_bf16(a[m], bg[n], accg[m][n], 0, 0, 0);
                    accu[m][n] = __builtin_amdgcn_mfma_f32_16x16x32_bf16(a[m], bu[n], accu[m][n], 0, 0, 0);
                }
        }
        __syncthreads();
    }

    #pragma unroll
    for (int m = 0; m < 4; ++m) {
        int rb = wm * 64 + m * 16 + lhi * 4;
        #pragma unroll
        for (int q = 0; q < 4; ++q) {
            int r = rb + q;
            size_t orow = (size_t)(start + r) * ID + i0 + wn * 64;
            #pragma unroll
            for (int n = 0; n < 4; ++n) {
                float g = accg[m][n][q], uu = accu[m][n][q];
                float a = g / (1.f + __expf(-g)) * uu;
                act16[orow + n * 16 + l15] = f2bf(a);
            }
        }
    }
}

// ---------------- GEMM2: out[t,:] += w * (act Wd); tile 128pair x 256h ----------------
__global__ __launch_bounds__(256, 2)
void gemm2_kernel(const unsigned short* __restrict__ act16, const unsigned short* __restrict__ WD,
                  const int* __restrict__ token_list,
                  const int* __restrict__ tE, const int* __restrict__ tStart,
                  const int* __restrict__ tCnt, const float* __restrict__ topk_w,
                  float* __restrict__ out) {
    int tile = blockIdx.x / 8, ht = blockIdx.x % 8;
    int e = tE[tile];
    if (e < 0) return;
    int start = tStart[tile], cnt = tCnt[tile];
    int h0 = ht * 256;

    __shared__ __align__(16) unsigned short As[128 * 64];
    __shared__ __align__(16) unsigned short Bs[256 * 64];
    __shared__ int   rowTok[128];
    __shared__ float rowW[128];

    int tid = threadIdx.x;
    if (tid < 128) {
        if (tid < cnt) { int v = token_list[start + tid]; rowTok[tid] = v >> 3; rowW[tid] = topk_w[v]; }
        else           { rowTok[tid] = 0;                 rowW[tid] = 0.f; }
    }
    __syncthreads();

    int lane = tid & 63, w = tid >> 6;
    int sub = lane & 7, lrow = lane >> 3;

    const unsigned short* aP[4]; const unsigned short* bP[8];
    #pragma unroll
    for (int c = 0; c < 4; ++c) {
        int q = w * 4 + c;
        int r = q * 8 + lrow;
        int chunk = (sub ^ (r & 7)) * 8;
        aP[c] = act16 + (size_t)(start + r) * ID + chunk;
    }
    #pragma unroll
    for (int c = 0; c < 8; ++c) {
        int q = w * 8 + c;
        int r = q * 8 + lrow;
        int chunk = (sub ^ (r & 7)) * 8;
        bP[c] = WD + ((size_t)e * HD + h0 + r) * ID + chunk;
    }

    f32x4 acc[4][8];
    #pragma unroll
    for (int m = 0; m < 4; ++m)
        #pragma unroll
        for (int n = 0; n < 8; ++n) { f32x4 z = {0.f, 0.f, 0.f, 0.f}; acc[m][n] = z; }

    int wm = w >> 1, wn = w & 1, l15 = lane & 15, lhi = lane >> 4;
    const bf16x8* Af = (const bf16x8*)As;
    const bf16x8* Bf = (const bf16x8*)Bs;

    for (int k0 = 0; k0 < ID; k0 += 64) {
        #pragma unroll
        for (int c = 0; c < 4; ++c) {
            int q = w * 4 + c;
            gload16(aP[c] + k0, (char*)As + q * 1024);
        }
        #pragma unroll
        for (int c = 0; c < 8; ++c) {
            int q = w * 8 + c;
            gload16(bP[c] + k0, (char*)Bs + q * 1024);
        }
        __syncthreads();
        #pragma unroll
        for (int ks = 0; ks < 2; ++ks) {
            int cc = ks * 4 + lhi;
            bf16x8 a[4], b[8];
            #pragma unroll
            for (int m = 0; m < 4; ++m) { int r = wm * 64 + m * 16 + l15; a[m] = Af[r * 8 + (cc ^ (r & 7))]; }
            #pragma unroll
            for (int n = 0; n < 8; ++n) { int r = wn * 128 + n * 16 + l15; b[n] = Bf[r * 8 + (cc ^ (r & 7))]; }
            #pragma unroll
            for (int m = 0; m < 4; ++m)
                #pragma unroll
                for (int n = 0; n < 8; ++n)
                    acc[m][n] = __builtin_amdgcn_mfma_f32_16x16x32_bf16(a[m], b[n], acc[m][n], 0, 0, 0);
        }
        __syncthreads();
    }

    #pragma unroll
    for (int m = 0; m < 4; ++m) {
        int rb = wm * 64 + m * 16 + lhi * 4;
        #pragma unroll
        for (int q = 0; q < 4; ++q) {
            int r = rb + q;
            if (r < cnt) {
                int tok = rowTok[r];
                float wgt = rowW[r];
                float* orow = out + (size_t)tok * HD + h0 + wn * 128;
                #pragma unroll
                for (int n = 0; n < 8; ++n)
                    atomicAdd(&orow[n * 16 + l15], acc[m][n][q] * wgt);
            }
        }
    }
}

extern "C" void kernel_launch(void* const* d_in, const int* in_sizes, int n_in,
                              void* d_out, int out_size, void* d_ws, size_t ws_size,
                              hipStream_t stream) {
    const float* x   = (const float*)d_in[0];
    const float* wg  = (const float*)d_in[1];
    const float* wgp = (const float*)d_in[2];
    const float* wup = (const float*)d_in[3];
    const float* wdp = (const float*)d_in[4];
    float* out = (float*)d_out;

    char* ws = (char*)d_ws;
    size_t off = 0;
    unsigned short* X16   = (unsigned short*)(ws + off); off += (size_t)T_TOK * HD * 2;      // 8 MB
    unsigned short* act16 = (unsigned short*)(ws + off); off += (size_t)MAXT * 128 * ID * 2; // 31.5 MB
    int*   topk_idx   = (int*)(ws + off);   off += NPAIR * 4;
    float* topk_w     = (float*)(ws + off); off += NPAIR * 4;
    int*   token_list = (int*)(ws + off);   off += MAXT * 128 * 4;
    int*   counts     = (int*)(ws + off);   off += 256;
    int*   cursor     = (int*)(ws + off);   off += 256;
    int*   tE         = (int*)(ws + off);   off += MAXT * 4;
    int*   tStart     = (int*)(ws + off);   off += MAXT * 4;
    int*   tCnt       = (int*)(ws + off);   off += MAXT * 4;
    off = (off + 255) & ~(size_t)255;
    unsigned short* WG = (unsigned short*)(ws + off); off += (size_t)NE * ID * HD * 2;       // 100.7 MB
    unsigned short* WU = (unsigned short*)(ws + off); off += (size_t)NE * ID * HD * 2;
    unsigned short* WD = (unsigned short*)(ws + off); off += (size_t)NE * HD * ID * 2;
    (void)in_sizes; (void)n_in; (void)out_size; (void)ws_size;

    hipMemsetAsync(counts, 0, 256, stream);
    hipMemsetAsync(d_out, 0, (size_t)T_TOK * HD * 4, stream);

    // fused prep: WG/WU/WD transpose+cvt (async 64x256 strips), X cvt, router -- one dispatch
    prep_all<<<NT_GU2 + NT_GU2 + NT_D2 + NB_CVT + NB_RTR, 256, 0, stream>>>(
        x, wg, wgp, wup, wdp, X16, WG, WU, WD, topk_idx, topk_w, counts);

    build_tiles<<<1, 64, 0, stream>>>(counts, cursor, tE, tStart, tCnt);
    scatter_kernel<<<NPAIR / 256, 256, 0, stream>>>(topk_idx, cursor, token_list);

    gemm1_kernel<<<MAXT * 6, 256, 0, stream>>>(X16, WG, WU, token_list, tE, tStart, tCnt, act16);
    gemm2_kernel<<<MAXT * 8, 256, 0, stream>>>(act16, WD, token_list, tE, tStart, tCnt, topk_w, out);
}

// Round 8
// 636.130 us; speedup vs baseline: 1.0094x; 1.0094x over previous
//
#include <hip/hip_runtime.h>

#define T_TOK 2048
#define HD    2048
#define NE    32
#define ID    768
#define TOPK  8
#define NPAIR (T_TOK * TOPK)
#define MAXT  160                            // max padded tiles: NPAIR/128 + NE

typedef short bf16x8 __attribute__((ext_vector_type(8)));
typedef float f32x4  __attribute__((ext_vector_type(4)));

__device__ inline unsigned short f2bf(float f) {
    unsigned u = __builtin_bit_cast(unsigned, f);
    u += 0x7FFF + ((u >> 16) & 1);          // round-to-nearest-even
    return (unsigned short)(u >> 16);
}

__device__ inline void gload16(const void* g, void* l) {
    __builtin_amdgcn_global_load_lds(
        (const __attribute__((address_space(1))) unsigned*)g,
        (__attribute__((address_space(3))) unsigned*)l, 16, 0, 0);
}

// ================= fused prep: transpose->BLOCKED layout + cvt_x + router =================
// Strip: src [.][C] f32 rows r0..r0+63 (k), cols c0..c0+255 (n) -> one contiguous 32KB
// blocked tile dstr[n_loc 256][k_loc 64] bf16. Phase 1: 16x global_load_lds/thread
// (swizzled global source, rule #21). Phase 2: 8x ds_read_b32, pack, 16B stores that are
// LINEAR in thread index -> pure sequential 32KB stream per block (write-run fix).

#define NT_GU2 3072                          // (HD/64)*(ID/256)*NE = 32*3*32
#define NT_D2  3072                          // (ID/64)*(HD/256)*NE = 12*8*32
#define NB_CVT 2048                          // T_TOK*HD/(256*8)
#define NB_RTR 2048                          // T_TOK

__device__ inline void transpose_strip(const float* __restrict__ src, unsigned short* __restrict__ dstr,
                                       int C, int r0, int c0, char* lds) {
    int tid = threadIdx.x;
    int w = tid >> 6, l = tid & 63;
    // phase 1: async loads. LDS row s linear; lane l sources global chunk l ^ ((s>>3)&7).
    #pragma unroll
    for (int q = 0; q < 16; ++q) {
        int s = w * 16 + q;
        const float* gp = src + (size_t)(r0 + s) * C + c0 + ((l ^ ((s >> 3) & 7)) << 2);
        gload16(gp, lds + s * 1024);         // wave-uniform LDS base; HW adds lane*16
    }
    __syncthreads();
    // phase 2: thread idx -> (n_loc c, k-octet tt); read 8 f32 down rows, pack, store 16B.
    // dst byte offset = idx*16 -> fully sequential across the block.
    #pragma unroll
    for (int jj = 0; jj < 8; ++jj) {
        int idx = tid + 256 * jj;            // 0..2047
        int c = idx >> 3, tt = idx & 7;
        const char* base = lds + tt * 8192 + ((((c >> 2) ^ tt) << 4) | ((c & 3) << 2));
        unsigned short o[8];
        #pragma unroll
        for (int j = 0; j < 8; ++j)
            o[j] = f2bf(*(const float*)(base + j * 1024));
        uint4 v;
        unsigned* pv = (unsigned*)&v;
        pv[0] = (unsigned)o[0] | ((unsigned)o[1] << 16);
        pv[1] = (unsigned)o[2] | ((unsigned)o[3] << 16);
        pv[2] = (unsigned)o[4] | ((unsigned)o[5] << 16);
        pv[3] = (unsigned)o[6] | ((unsigned)o[7] << 16);
        *(uint4*)&dstr[(size_t)idx * 8] = v;
    }
}

__global__ __launch_bounds__(256)
void prep_all(const float* __restrict__ x, const float* __restrict__ wg,
              const float* __restrict__ wgp, const float* __restrict__ wup,
              const float* __restrict__ wdp,
              unsigned short* __restrict__ X16,
              unsigned short* __restrict__ WG, unsigned short* __restrict__ WU,
              unsigned short* __restrict__ WD,
              int* __restrict__ topk_idx, float* __restrict__ topk_w,
              int* __restrict__ counts) {
    __shared__ __align__(16) char lds[65536];
    int bid = blockIdx.x;

    if (bid < NT_GU2) {                      // WG: [HD][ID] -> blk[i_blk][k_blk(32)][256][64]
        int e = bid / 96, ti = bid % 96;
        int r0 = (ti & 31) * 64, c0 = (ti >> 5) * 256;  // r over HD(32), c over ID(3)
        unsigned short* dstr = WG + (size_t)e * HD * ID
                             + ((size_t)(c0 >> 8) * 32 + (r0 >> 6)) * 16384;
        transpose_strip(wgp + (size_t)e * HD * ID, dstr, ID, r0, c0, lds);
        return;
    }
    bid -= NT_GU2;
    if (bid < NT_GU2) {                      // WU
        int e = bid / 96, ti = bid % 96;
        int r0 = (ti & 31) * 64, c0 = (ti >> 5) * 256;
        unsigned short* dstr = WU + (size_t)e * HD * ID
                             + ((size_t)(c0 >> 8) * 32 + (r0 >> 6)) * 16384;
        transpose_strip(wup + (size_t)e * HD * ID, dstr, ID, r0, c0, lds);
        return;
    }
    bid -= NT_GU2;
    if (bid < NT_D2) {                       // WD: [ID][HD] -> blk[h_blk][k_blk(12)][256][64]
        int e = bid / 96, ti = bid % 96;
        int r0 = (ti % 12) * 64, c0 = (ti / 12) * 256;  // r over ID(12), c over HD(8)
        unsigned short* dstr = WD + (size_t)e * ID * HD
                             + ((size_t)(c0 >> 8) * 12 + (r0 >> 6)) * 16384;
        transpose_strip(wdp + (size_t)e * ID * HD, dstr, HD, r0, c0, lds);
        return;
    }
    bid -= NT_D2;
    if (bid < NB_CVT) {                      // X -> bf16
        int i = bid * 256 + threadIdx.x;
        const float4* src = (const float4*)x + (size_t)i * 2;
        float4 a = src[0], b = src[1];
        uint4 r;
        r.x = (unsigned)f2bf(a.x) | ((unsigned)f2bf(a.y) << 16);
        r.y = (unsigned)f2bf(a.z) | ((unsigned)f2bf(a.w) << 16);
        r.z = (unsigned)f2bf(b.x) | ((unsigned)f2bf(b.y) << 16);
        r.w = (unsigned)f2bf(b.z) | ((unsigned)f2bf(b.w) << 16);
        *(uint4*)(X16 + (size_t)i * 8) = r;
        return;
    }
    bid -= NB_CVT;
    {                                        // router, one block per token
        int t = bid;
        int tid = threadIdx.x;
        int e = tid & 31, seg = tid >> 5;
        const float* xr = x + (size_t)t * HD + seg * 256;
        const float* wp = wg + (size_t)(seg * 256) * NE + e;
        float acc = 0.f;
        #pragma unroll 4
        for (int j = 0; j < 256; ++j) acc += xr[j] * wp[j * NE];
        float* part = (float*)lds;           // [8][33]
        float* lg = part + 8 * 33;           // [32]
        part[seg * 33 + e] = acc;
        __syncthreads();
        if (tid < 32) {
            float s = 0.f;
            #pragma unroll
            for (int g = 0; g < 8; ++g) s += part[g * 33 + tid];
            lg[tid] = s;
        }
        __syncthreads();
        if (tid == 0) {
            float m = lg[0];
            for (int i = 1; i < 32; ++i) m = fmaxf(m, lg[i]);
            for (int i = 0; i < 32; ++i) lg[i] = __expf(lg[i] - m);
            int   idxs[TOPK]; float wv[TOPK]; float wsum = 0.f;
            #pragma unroll
            for (int k = 0; k < TOPK; ++k) {
                float best = -1.f; int bi = 0;
                for (int i = 0; i < 32; ++i) if (lg[i] > best) { best = lg[i]; bi = i; }
                idxs[k] = bi; wv[k] = best; wsum += best; lg[bi] = -1.f;
            }
            #pragma unroll
            for (int k = 0; k < TOPK; ++k) {
                topk_idx[t * TOPK + k] = idxs[k];
                topk_w[t * TOPK + k]   = wv[k] / wsum;
                atomicAdd(&counts[idxs[k]], 1);
            }
        }
    }
}

// ---------------- build padded tile table (1 thread; negligible) ----------------
__global__ void build_tiles(const int* __restrict__ counts, int* __restrict__ cursor,
                            int* __restrict__ tE, int* __restrict__ tStart,
                            int* __restrict__ tCnt) {
    if (threadIdx.x == 0 && blockIdx.x == 0) {
        int run = 0, nt = 0;
        for (int e = 0; e < NE; ++e) {
            cursor[e] = run;
            int c = counts[e];
            int nte = (c + 127) >> 7;
            for (int j = 0; j < nte; ++j) {
                tE[nt] = e;
                tStart[nt] = run + j * 128;
                tCnt[nt] = (c - j * 128 < 128) ? (c - j * 128) : 128;
                ++nt;
            }
            run += nte * 128;
        }
        for (; nt < MAXT; ++nt) { tE[nt] = -1; tStart[nt] = 0; tCnt[nt] = 0; }
    }
}

__global__ void scatter_kernel(const int* __restrict__ topk_idx, int* __restrict__ cursor,
                               int* __restrict__ token_list) {
    int i = blockIdx.x * 256 + threadIdx.x;
    int e = topk_idx[i];
    int pos = atomicAdd(&cursor[e], 1);
    token_list[pos] = i;
}

// ---------------- GEMM1: act = silu(X Wg) * (X Wu); tile 128pair x 128i ----------------
__global__ __launch_bounds__(256, 2)
void gemm1_kernel(const unsigned short* __restrict__ X16,
                  const unsigned short* __restrict__ WG, const unsigned short* __restrict__ WU,
                  const int* __restrict__ token_list,
                  const int* __restrict__ tE, const int* __restrict__ tStart,
                  const int* __restrict__ tCnt, unsigned short* __restrict__ act16) {
    int tile = blockIdx.x / 6, it = blockIdx.x % 6;
    int e = tE[tile];
    if (e < 0) return;
    int start = tStart[tile], cnt = tCnt[tile];
    int i0 = it * 128;

    __shared__ __align__(16) unsigned short As[128 * 64];
    __shared__ __align__(16) unsigned short Bg[128 * 64];
    __shared__ __align__(16) unsigned short Bu[128 * 64];
    __shared__ int rowTok[128];

    int tid = threadIdx.x;
    if (tid < 128)
        rowTok[tid] = (tid < cnt) ? (token_list[start + tid] >> 3) : 0;
    __syncthreads();

    int lane = tid & 63, w = tid >> 6;
    int sub = lane & 7, lrow = lane >> 3;

    // blocked B: elem addr = ((i_blk*32 + k_blk)*256 + i_loc)*64 + chunk; k-step adds k0*256
    const unsigned short* aP[4]; const unsigned short* gP[4]; const unsigned short* uP[4];
    #pragma unroll
    for (int c = 0; c < 4; ++c) {
        int q = w * 4 + c;
        int r = q * 8 + lrow;
        int chunk = (sub ^ (r & 7)) * 8;
        aP[c] = X16 + (size_t)rowTok[r] * HD + chunk;
        int i = i0 + r;
        size_t bbase = ((size_t)((i >> 8) * 32) * 256 + (i & 255)) * 64 + chunk;
        gP[c] = WG + (size_t)e * ID * HD + bbase;
        uP[c] = WU + (size_t)e * ID * HD + bbase;
    }

    f32x4 accg[4][4], accu[4][4];
    #pragma unroll
    for (int m = 0; m < 4; ++m)
        #pragma unroll
        for (int n = 0; n < 4; ++n) {
            f32x4 z = {0.f, 0.f, 0.f, 0.f};
            accg[m][n] = z; accu[m][n] = z;
        }

    int wm = w >> 1, wn = w & 1, l15 = lane & 15, lhi = lane >> 4;
    const bf16x8* Af = (const bf16x8*)As;
    const bf16x8* Gf = (const bf16x8*)Bg;
    const bf16x8* Uf = (const bf16x8*)Bu;

    for (int k0 = 0; k0 < HD; k0 += 64) {
        #pragma unroll
        for (int c = 0; c < 4; ++c) {
            int q = w * 4 + c;
            gload16(aP[c] + k0, (char*)As + q * 1024);
            gload16(gP[c] + (size_t)k0 * 256, (char*)Bg + q * 1024);
            gload16(uP[c] + (size_t)k0 * 256, (char*)Bu + q * 1024);
        }
        __syncthreads();
        #pragma unroll
        for (int ks = 0; ks < 2; ++ks) {
            int cc = ks * 4 + lhi;
            bf16x8 a[4], bg[4], bu[4];
            #pragma unroll
            for (int m = 0; m < 4; ++m) { int r = wm * 64 + m * 16 + l15; a[m] = Af[r * 8 + (cc ^ (r & 7))]; }
            #pragma unroll
            for (int n = 0; n < 4; ++n) {
                int r = wn * 64 + n * 16 + l15;
                bg[n] = Gf[r * 8 + (cc ^ (r & 7))];
                bu[n] = Uf[r * 8 + (cc ^ (r & 7))];
            }
            #pragma unroll
            for (int m = 0; m < 4; ++m)
                #pragma unroll
                for (int n = 0; n < 4; ++n) {
                    accg[m][n] = __builtin_amdgcn_mfma_f32_16x16x32_bf16(a[m], bg[n], accg[m][n], 0, 0, 0);
                    accu[m][n] = __builtin_amdgcn_mfma_f32_16x16x32_bf16(a[m], bu[n], accu[m][n], 0, 0, 0);
                }
        }
        __syncthreads();
    }

    #pragma unroll
    for (int m = 0; m < 4; ++m) {
        int rb = wm * 64 + m * 16 + lhi * 4;
        #pragma unroll
        for (int q = 0; q < 4; ++q) {
            int r = rb + q;
            size_t orow = (size_t)(start + r) * ID + i0 + wn * 64;
            #pragma unroll
            for (int n = 0; n < 4; ++n) {
                float g = accg[m][n][q], uu = accu[m][n][q];
                float a = g / (1.f + __expf(-g)) * uu;
                act16[orow + n * 16 + l15] = f2bf(a);
            }
        }
    }
}

// ---------------- GEMM2: out[t,:] += w * (act Wd); tile 128pair x 256h ----------------
__global__ __launch_bounds__(256, 2)
void gemm2_kernel(const unsigned short* __restrict__ act16, const unsigned short* __restrict__ WD,
                  const int* __restrict__ token_list,
                  const int* __restrict__ tE, const int* __restrict__ tStart,
                  const int* __restrict__ tCnt, const float* __restrict__ topk_w,
                  float* __restrict__ out) {
    int tile = blockIdx.x / 8, ht = blockIdx.x % 8;
    int e = tE[tile];
    if (e < 0) return;
    int start = tStart[tile], cnt = tCnt[tile];
    int h0 = ht * 256;

    __shared__ __align__(16) unsigned short As[128 * 64];
    __shared__ __align__(16) unsigned short Bs[256 * 64];
    __shared__ int   rowTok[128];
    __shared__ float rowW[128];

    int tid = threadIdx.x;
    if (tid < 128) {
        if (tid < cnt) { int v = token_list[start + tid]; rowTok[tid] = v >> 3; rowW[tid] = topk_w[v]; }
        else           { rowTok[tid] = 0;                 rowW[tid] = 0.f; }
    }
    __syncthreads();

    int lane = tid & 63, w = tid >> 6;
    int sub = lane & 7, lrow = lane >> 3;

    const unsigned short* aP[4]; const unsigned short* bP[8];
    #pragma unroll
    for (int c = 0; c < 4; ++c) {
        int q = w * 4 + c;
        int r = q * 8 + lrow;
        int chunk = (sub ^ (r & 7)) * 8;
        aP[c] = act16 + (size_t)(start + r) * ID + chunk;
    }
    // blocked B: elem addr = ((h_blk*12 + k_blk)*256 + h_loc)*64 + chunk; k-step adds k0*256
    #pragma unroll
    for (int c = 0; c < 8; ++c) {
        int q = w * 8 + c;
        int r = q * 8 + lrow;                // h_loc 0..255, h_blk = ht
        int chunk = (sub ^ (r & 7)) * 8;
        bP[c] = WD + (size_t)e * HD * ID + ((size_t)(ht * 12) * 256 + r) * 64 + chunk;
    }

    f32x4 acc[4][8];
    #pragma unroll
    for (int m = 0; m < 4; ++m)
        #pragma unroll
        for (int n = 0; n < 8; ++n) { f32x4 z = {0.f, 0.f, 0.f, 0.f}; acc[m][n] = z; }

    int wm = w >> 1, wn = w & 1, l15 = lane & 15, lhi = lane >> 4;
    const bf16x8* Af = (const bf16x8*)As;
    const bf16x8* Bf = (const bf16x8*)Bs;

    for (int k0 = 0; k0 < ID; k0 += 64) {
        #pragma unroll
        for (int c = 0; c < 4; ++c) {
            int q = w * 4 + c;
            gload16(aP[c] + k0, (char*)As + q * 1024);
        }
        #pragma unroll
        for (int c = 0; c < 8; ++c) {
            int q = w * 8 + c;
            gload16(bP[c] + (size_t)k0 * 256, (char*)Bs + q * 1024);
        }
        __syncthreads();
        #pragma unroll
        for (int ks = 0; ks < 2; ++ks) {
            int cc = ks * 4 + lhi;
            bf16x8 a[4], b[8];
            #pragma unroll
            for (int m = 0; m < 4; ++m) { int r = wm * 64 + m * 16 + l15; a[m] = Af[r * 8 + (cc ^ (r & 7))]; }
            #pragma unroll
            for (int n = 0; n < 8; ++n) { int r = wn * 128 + n * 16 + l15; b[n] = Bf[r * 8 + (cc ^ (r & 7))]; }
            #pragma unroll
            for (int m = 0; m < 4; ++m)
                #pragma unroll
                for (int n = 0; n < 8; ++n)
                    acc[m][n] = __builtin_amdgcn_mfma_f32_16x16x32_bf16(a[m], b[n], acc[m][n], 0, 0, 0);
        }
        __syncthreads();
    }

    #pragma unroll
    for (int m = 0; m < 4; ++m) {
        int rb = wm * 64 + m * 16 + lhi * 4;
        #pragma unroll
        for (int q = 0; q < 4; ++q) {
            int r = rb + q;
            if (r < cnt) {
                int tok = rowTok[r];
                float wgt = rowW[r];
                float* orow = out + (size_t)tok * HD + h0 + wn * 128;
                #pragma unroll
                for (int n = 0; n < 8; ++n)
                    atomicAdd(&orow[n * 16 + l15], acc[m][n][q] * wgt);
            }
        }
    }
}

extern "C" void kernel_launch(void* const* d_in, const int* in_sizes, int n_in,
                              void* d_out, int out_size, void* d_ws, size_t ws_size,
                              hipStream_t stream) {
    const float* x   = (const float*)d_in[0];
    const float* wg  = (const float*)d_in[1];
    const float* wgp = (const float*)d_in[2];
    const float* wup = (const float*)d_in[3];
    const float* wdp = (const float*)d_in[4];
    float* out = (float*)d_out;

    char* ws = (char*)d_ws;
    size_t off = 0;
    unsigned short* X16   = (unsigned short*)(ws + off); off += (size_t)T_TOK * HD * 2;      // 8 MB
    unsigned short* act16 = (unsigned short*)(ws + off); off += (size_t)MAXT * 128 * ID * 2; // 31.5 MB
    int*   topk_idx   = (int*)(ws + off);   off += NPAIR * 4;
    float* topk_w     = (float*)(ws + off); off += NPAIR * 4;
    int*   token_list = (int*)(ws + off);   off += MAXT * 128 * 4;
    int*   counts     = (int*)(ws + off);   off += 256;
    int*   cursor     = (int*)(ws + off);   off += 256;
    int*   tE         = (int*)(ws + off);   off += MAXT * 4;
    int*   tStart     = (int*)(ws + off);   off += MAXT * 4;
    int*   tCnt       = (int*)(ws + off);   off += MAXT * 4;
    off = (off + 255) & ~(size_t)255;
    unsigned short* WG = (unsigned short*)(ws + off); off += (size_t)NE * ID * HD * 2;       // 100.7 MB
    unsigned short* WU = (unsigned short*)(ws + off); off += (size_t)NE * ID * HD * 2;
    unsigned short* WD = (unsigned short*)(ws + off); off += (size_t)NE * HD * ID * 2;
    (void)in_sizes; (void)n_in; (void)out_size; (void)ws_size;

    hipMemsetAsync(counts, 0, 256, stream);
    hipMemsetAsync(d_out, 0, (size_t)T_TOK * HD * 4, stream);

    // fused prep: WG/WU/WD transpose+cvt into BLOCKED layout, X cvt, router -- one dispatch
    prep_all<<<NT_GU2 + NT_GU2 + NT_D2 + NB_CVT + NB_RTR, 256, 0, stream>>>(
        x, wg, wgp, wup, wdp, X16, WG, WU, WD, topk_idx, topk_w, counts);

    build_tiles<<<1, 64, 0, stream>>>(counts, cursor, tE, tStart, tCnt);
    scatter_kernel<<<NPAIR / 256, 256, 0, stream>>>(topk_idx, cursor, token_list);

    gemm1_kernel<<<MAXT * 6, 256, 0, stream>>>(X16, WG, WU, token_list, tE, tStart, tCnt, act16);
    gemm2_kernel<<<MAXT * 8, 256, 0, stream>>>(act16, WD, token_list, tE, tStart, tCnt, topk_w, out);
}